// Round 15
// baseline (269.151 us; speedup 1.0000x reference)
//
#include <hip/hip_runtime.h>

// Problem constants: B=2, L=4096, D_MODEL=512, HEAD=8, D_K=64,
// N_BUCKETS=128, ROUNDS=4, 64 chunks of 64 sorted positions, window=128.
#define L4   4096
#define DK   64
#define NR   4
#define NB   128
#define WIN  128
#define DM   512
#define BH   16
#define BIGF 1000000000.0f

typedef short v8s __attribute__((ext_vector_type(8)));
typedef float v4f __attribute__((ext_vector_type(4)));

__device__ __forceinline__ unsigned short f2bf(float x) {
  union { float f; unsigned u; } v; v.f = x;
  const unsigned r = (v.u + 0x7FFFu + ((v.u >> 16) & 1u)) >> 16;
  return (unsigned short)r;
}
__device__ __forceinline__ float bf2f(unsigned short u) {
  union { unsigned u; float f; } v; v.u = ((unsigned)u) << 16;
  return v.f;
}
__device__ __forceinline__ ushort4 f2bf4(const float4 x) {
  ushort4 r; r.x = f2bf(x.x); r.y = f2bf(x.y); r.z = f2bf(x.z); r.w = f2bf(x.w);
  return r;
}

// ---- static device workspace (deterministic, fully rewritten per call) ----
__device__ float g_fqn[(size_t)BH * L4 * DK];            // normalized q f32 (hash path)
__device__ unsigned short g_fqb[(size_t)BH * L4 * DK];   // normalized q bf16 (scores)
__device__ unsigned short g_fvb[(size_t)BH * L4 * DK];   // v bf16 (PV)
__device__ float g_rmnT[NR * 64 * DK];                   // normalized rand matrix [r][k][d]
__device__ int   g_hash [BH * NR * L4];
__device__ int   g_sidx [BH * NR * L4];                  // sorted pos -> original l
__device__ int   g_shash[BH * NR * L4];
__device__ int   g_inv  [BH * NR * L4];                  // original l -> sorted pos
__device__ unsigned char g_cnt[(size_t)BH * L4 * WIN];   // packed dup-key counts: n0|n1<<3|n2<<6
__device__ float2 g_stat[BH * NR * L4];                  // per-round row (max, sumexp) by spos
__device__ float2 g_MZ  [BH * L4];                       // merged (M, 1/Z) by original l
__device__ unsigned short g_osortb[(size_t)BH * NR * L4 * DK]; // UNNORMALIZED per-round out bf16, sorted
__device__ unsigned short g_xb[(size_t)2 * L4 * DM];     // concat-head attention out (bf16)

// ===== stage 1 (R10 best-known structure, exact): range-split
// blocks [0,512): qproj | [512,1024): V-proj MFMA | [1024,1088): rmnorm
__global__ __launch_bounds__(256) void stage1_kernel(const float* __restrict__ A,
                                                     const float* __restrict__ Wq,
                                                     const float* __restrict__ bq,
                                                     const float* __restrict__ Vf,
                                                     const float* __restrict__ Wv,
                                                     const float* __restrict__ bv,
                                                     const float* __restrict__ rm)
{
  __shared__ __align__(16) char smem[27648];
  const int bid = blockIdx.x;
  const int tid = threadIdx.x;
  if (bid < 512) {
    // ---------------- qproj body (R9/R10 passing version) ----------------
    float (*As)[132] = (float(*)[132])smem;                 // 16896 B
    float (*Bs)[68]  = (float(*)[68])(smem + 16896);        //  8704 B
    const int m0 = (bid & 63) * 128;
    const int n0 = (bid >> 6) * 64;
    const int am = tid & 127, ak0 = (tid >> 7) * 16;
    const int bn = tid & 63,  bk0 = (tid >> 6) * 8;
    const float* arow = A + (size_t)(m0 + am) * DM + ak0;
    const float* brow = Wq + (size_t)(n0 + bn) * DM + bk0;
    float4 pa0 = *(const float4*)(arow);
    float4 pa1 = *(const float4*)(arow + 4);
    float4 pa2 = *(const float4*)(arow + 8);
    float4 pa3 = *(const float4*)(arow + 12);
    float4 pb0 = *(const float4*)(brow);
    float4 pb1 = *(const float4*)(brow + 4);
    const int lane = tid & 63, w = tid >> 6;
    const int ng = lane & 15, mgl = lane >> 4;
    const int mbase = (w * 4 + mgl) * 8;
    const int nbase = ng * 4;
    float acc[8][4] = {};
    for (int kt = 0; kt < DM; kt += 32) {
      __syncthreads();
      As[ak0 +  0][am] = pa0.x; As[ak0 +  1][am] = pa0.y; As[ak0 +  2][am] = pa0.z; As[ak0 +  3][am] = pa0.w;
      As[ak0 +  4][am] = pa1.x; As[ak0 +  5][am] = pa1.y; As[ak0 +  6][am] = pa1.z; As[ak0 +  7][am] = pa1.w;
      As[ak0 +  8][am] = pa2.x; As[ak0 +  9][am] = pa2.y; As[ak0 + 10][am] = pa2.z; As[ak0 + 11][am] = pa2.w;
      As[ak0 + 12][am] = pa3.x; As[ak0 + 13][am] = pa3.y; As[ak0 + 14][am] = pa3.z; As[ak0 + 15][am] = pa3.w;
      Bs[bk0 + 0][bn] = pb0.x; Bs[bk0 + 1][bn] = pb0.y; Bs[bk0 + 2][bn] = pb0.z; Bs[bk0 + 3][bn] = pb0.w;
      Bs[bk0 + 4][bn] = pb1.x; Bs[bk0 + 5][bn] = pb1.y; Bs[bk0 + 6][bn] = pb1.z; Bs[bk0 + 7][bn] = pb1.w;
      __syncthreads();
      if (kt + 32 < DM) {
        pa0 = *(const float4*)(arow + kt + 32);
        pa1 = *(const float4*)(arow + kt + 36);
        pa2 = *(const float4*)(arow + kt + 40);
        pa3 = *(const float4*)(arow + kt + 44);
        pb0 = *(const float4*)(brow + kt + 32);
        pb1 = *(const float4*)(brow + kt + 36);
      }
      #pragma unroll
      for (int kk = 0; kk < 32; ++kk) {
        const float4 a0 = *(const float4*)&As[kk][mbase];
        const float4 a1 = *(const float4*)&As[kk][mbase + 4];
        const float4 bv4 = *(const float4*)&Bs[kk][nbase];
        const float amv[8] = {a0.x, a0.y, a0.z, a0.w, a1.x, a1.y, a1.z, a1.w};
        const float bnv[4] = {bv4.x, bv4.y, bv4.z, bv4.w};
        #pragma unroll
        for (int i = 0; i < 8; ++i)
          #pragma unroll
          for (int j = 0; j < 4; ++j)
            acc[i][j] = fmaf(amv[i], bnv[j], acc[i][j]);
      }
    }
    #pragma unroll
    for (int j = 0; j < 4; ++j) {
      const float bb = bq[n0 + nbase + j];
      #pragma unroll
      for (int i = 0; i < 8; ++i) acc[i][j] += bb;
    }
    float sc[8];
    #pragma unroll
    for (int i = 0; i < 8; ++i) {
      float s = acc[i][0] * acc[i][0];
      s = fmaf(acc[i][1], acc[i][1], s);
      s = fmaf(acc[i][2], acc[i][2], s);
      s = fmaf(acc[i][3], acc[i][3], s);
      s += __shfl_xor(s, 1);
      s += __shfl_xor(s, 2);
      s += __shfl_xor(s, 4);
      s += __shfl_xor(s, 8);
      sc[i] = 1.0f / sqrtf(s);
    }
    const int bh = (m0 >> 12) * 8 + (n0 >> 6);
    const int lb = (m0 & (L4 - 1)) + mbase;
    #pragma unroll
    for (int i = 0; i < 8; ++i) {
      const size_t idx = ((size_t)bh * L4 + lb + i) * DK + nbase;
      float4 o;
      o.x = acc[i][0] * sc[i]; o.y = acc[i][1] * sc[i];
      o.z = acc[i][2] * sc[i]; o.w = acc[i][3] * sc[i];
      *(float4*)(g_fqn + idx) = o;
      *(ushort4*)(g_fqb + idx) = f2bf4(o);
    }
  } else if (bid < 1024) {
    // ------------- V projection, bf16 MFMA (unchanged body) -------------
    unsigned short (*As)[72] = (unsigned short(*)[72])smem;          // 18432 B
    unsigned short (*Bs)[72] = (unsigned short(*)[72])(smem + 18432); //  9216 B
    const int b2 = bid - 512;
    const int m0 = (b2 & 63) * 128;
    const int n0 = (b2 >> 6) * 64;
    const int lane = tid & 63, w = tid >> 6;
    const int li = lane & 15, lq = lane >> 4;
    v4f acc[2][4];
    #pragma unroll
    for (int mt = 0; mt < 2; ++mt)
      #pragma unroll
      for (int jt = 0; jt < 4; ++jt) acc[mt][jt] = (v4f){0.f, 0.f, 0.f, 0.f};
    for (int kt = 0; kt < DM; kt += 64) {
      __syncthreads();
      {
        const int row = tid >> 1, h = tid & 1;
        const float* src = Vf + (size_t)(m0 + row) * DM + kt + h * 32;
        #pragma unroll
        for (int u = 0; u < 4; ++u) {
          const float4 x = *(const float4*)(src + u * 8);
          const float4 y = *(const float4*)(src + u * 8 + 4);
          *(ushort4*)&As[row][h * 32 + u * 8]     = f2bf4(x);
          *(ushort4*)&As[row][h * 32 + u * 8 + 4] = f2bf4(y);
        }
      }
      {
        const int row = tid >> 2, p = tid & 3;
        const float* src = Wv + (size_t)(n0 + row) * DM + kt + p * 16;
        #pragma unroll
        for (int u = 0; u < 2; ++u) {
          const float4 x = *(const float4*)(src + u * 8);
          const float4 y = *(const float4*)(src + u * 8 + 4);
          *(ushort4*)&Bs[row][p * 16 + u * 8]     = f2bf4(x);
          *(ushort4*)&Bs[row][p * 16 + u * 8 + 4] = f2bf4(y);
        }
      }
      __syncthreads();
      #pragma unroll
      for (int ks = 0; ks < 2; ++ks) {
        const v8s aq0 = *(const v8s*)&As[w * 32 + li][ks * 32 + lq * 8];
        const v8s aq1 = *(const v8s*)&As[w * 32 + 16 + li][ks * 32 + lq * 8];
        #pragma unroll
        for (int jt = 0; jt < 4; ++jt) {
          const v8s bk = *(const v8s*)&Bs[jt * 16 + li][ks * 32 + lq * 8];
          acc[0][jt] = __builtin_amdgcn_mfma_f32_16x16x32_bf16(aq0, bk, acc[0][jt], 0, 0, 0);
          acc[1][jt] = __builtin_amdgcn_mfma_f32_16x16x32_bf16(aq1, bk, acc[1][jt], 0, 0, 0);
        }
      }
    }
    #pragma unroll
    for (int mt = 0; mt < 2; ++mt)
      #pragma unroll
      for (int jt = 0; jt < 4; ++jt)
        #pragma unroll
        for (int reg = 0; reg < 4; ++reg) {
          const int m = m0 + w * 32 + mt * 16 + lq * 4 + reg;
          const int n = n0 + jt * 16 + li;
          const float vv = acc[mt][jt][reg] + bv[n];
          const int bh = (m >> 12) * 8 + (n >> 6);
          const int l = m & (L4 - 1);
          g_fvb[((size_t)bh * L4 + l) * DK + (n & 63)] = f2bf(vv);
        }
  } else {
    // --- rmnorm body (4 rows/block) ---
    const int dr = (bid - 1024) * 4 + (tid >> 6);   // d*4 + r
    const int k = tid & 63;
    const float v = rm[dr * 64 + k];
    float s = v * v;
    #pragma unroll
    for (int off = 32; off; off >>= 1) s += __shfl_xor(s, off);
    const int d = dr >> 2, r = dr & 3;
    g_rmnT[(r * 64 + k) * DK + d] = v / sqrtf(s);
  }
}

// --------- hash: proj = fqn . rmn, argmax over [proj, -proj] (first index) ---------
__global__ __launch_bounds__(256, 4) void hash_kernel() {
  const int tid = threadIdx.x;
  const int w = __builtin_amdgcn_readfirstlane(tid >> 6);   // round (wave-uniform)
  const int lane = tid & 63;          // row within group
  const int row = blockIdx.x * 64 + lane;   // flattened bh*L4 + l
  float q[64];
  #pragma unroll
  for (int du = 0; du < 16; ++du) {
    const float4 v = *(const float4*)(g_fqn + (size_t)row * DK + du * 4);
    q[du * 4 + 0] = v.x; q[du * 4 + 1] = v.y;
    q[du * 4 + 2] = v.z; q[du * 4 + 3] = v.w;
  }
  const float* rmw = g_rmnT + w * (64 * DK);
  float bestP = -BIGF, bestN = -BIGF;
  int idxP = 0, idxN = 0;
  for (int k = 0; k < 64; k += 2) {
    const float* rp0 = rmw + k * DK;        // wave-uniform -> s_load
    const float* rp1 = rp0 + DK;
    float a0 = 0.f, a1 = 0.f;
    #pragma unroll
    for (int d = 0; d < 64; ++d) {
      a0 = fmaf(q[d], rp0[d], a0);
      a1 = fmaf(q[d], rp1[d], a1);
    }
    if (a0 > bestP)  { bestP = a0;  idxP = k; }
    if (-a0 > bestN) { bestN = -a0; idxN = k; }
    if (a1 > bestP)  { bestP = a1;  idxP = k + 1; }
    if (-a1 > bestN) { bestN = -a1; idxN = k + 1; }
  }
  const int idx = (bestP >= bestN) ? idxP : 64 + idxN;
  const int bh = row >> 12, l = row & (L4 - 1);
  g_hash[(bh * NR + w) * L4 + l] = idx;
}

// ------------- stable counting sort of 4096 hashes per (bh, round) -------------
__global__ __launch_bounds__(128) void sort_kernel() {
  __shared__ int chunkHist[64][NB];   // 32 KB
  __shared__ int tot[NB];
  __shared__ int binBase[NB];
  const int bhr = blockIdx.x;         // bh*4 + r
  const int t = threadIdx.x;
  const int* hrow = g_hash + bhr * L4;
  for (int idx = t; idx < 64 * NB; idx += 128) ((int*)chunkHist)[idx] = 0;
  __syncthreads();
  if (t < 64) {
    for (int e = 0; e < 64; ++e) chunkHist[t][hrow[t * 64 + e]]++;
  }
  __syncthreads();
  if (t < NB) { int s = 0; for (int cc = 0; cc < 64; ++cc) s += chunkHist[cc][t]; tot[t] = s; }
  __syncthreads();
  if (t == 0) { int run = 0; for (int h = 0; h < NB; ++h) { binBase[h] = run; run += tot[h]; } }
  __syncthreads();
  if (t < NB) {
    int run = binBase[t];
    for (int cc = 0; cc < 64; ++cc) { const int tmp = chunkHist[cc][t]; chunkHist[cc][t] = run; run += tmp; }
  }
  __syncthreads();
  if (t < 64) {
    for (int e = 0; e < 64; ++e) {
      const int l = t * 64 + e;
      const int h = hrow[l];
      const int p = chunkHist[t][h]++;
      g_sidx [bhr * L4 + p] = l;
      g_shash[bhr * L4 + p] = h;
      g_inv  [bhr * L4 + l] = p;
    }
  }
}

// ---- duplicate-key counts (bug-faithful), PACKED: n0 | n1<<3 | n2<<6 per byte ----
// (n0<=7: 3b, n1<=5: 3b, n2<=3: 2b; round 3's count is identically 1 -> not stored)
__global__ __launch_bounds__(256) void counts_kernel() {
  const int bh = blockIdx.x;
  const int l0 = blockIdx.y * 32;
  const int j = threadIdx.x & 127;
  const int lh = threadIdx.x >> 7;   // 0..1
  for (int u = 0; u < 16; ++u) {
    const int l = l0 + u * 2 + lh;
    int a[4];
    #pragma unroll
    for (int r = 0; r < NR; ++r) {
      const int base = (bh * NR + r) * L4;
      const int spos = g_inv[base + l];
      const int c = spos >> 6;
      // shared pad sentinel across rounds (reference's 1e9==1e9 pad equality)
      a[r] = (c == 0 && j < 64) ? (1 << 20) : g_sidx[base + c * 64 - 64 + j];
    }
    const int c01 = a[0] == a[1], c02 = a[0] == a[2], c03 = a[0] == a[3];
    const int c12 = a[1] == a[2], c13 = a[1] == a[3], c23 = a[2] == a[3];
    const int n0 = 1 + 2 * c01 + c02 + c03 + c12 + c23;
    const int n1 = 1 + c02 + c12 + 2 * c13;
    const int n2 = 1 + c03 + c23;
    g_cnt[((size_t)bh * L4 + l) * WIN + j] = (unsigned char)(n0 | (n1 << 3) | (n2 << 6));
  }
}

// ==== fused attention pass: MFMA QK^T + masks -> (m, Z) stat -> P'=exp(s-m) bf16
// in LDS -> V gather -> PV MFMA -> UNNORMALIZED O' bf16 to g_osortb.
// Softmax scale exp(m_r - M)/Z commutes with the j-sum -> deferred to combine.
__global__ __launch_bounds__(256) void passA_kernel() {
  const int c = blockIdx.x, r = blockIdx.y, bh = blockIdx.z;
  const int base = (bh * NR + r) * L4;
  const int s0 = c * 64;
  const bool use_cnt = (r != 3);   // round-3 counts are identically 1
  const int cnt_sh = (r == 2) ? 6 : r * 3;    // block-uniform unpack shift
  const int cnt_msk = (r == 2) ? 3 : 7;
  __shared__ __align__(16) char smem[35840];
  unsigned short (*Qb)[72] = (unsigned short(*)[72])smem;            //  9216 B
  unsigned short (*Kb)[72] = (unsigned short(*)[72])(smem + 9216);   // 18432 B
  unsigned char (*cnt8)[128] = (unsigned char(*)[128])(smem + 27648); // 8192 B
  unsigned short (*Pt)[136] = (unsigned short(*)[136])smem;          // 17408 B (phase 2)
  unsigned short (*Vt)[136] = (unsigned short(*)[136])(smem + 17408); // 17408 B (phase 2)
  __shared__ int qi_s[64], qh_s[64], ki_s[128], kh_s[128];
  __shared__ float lutl[9];
  const int tid = threadIdx.x;
  if (tid < 9) lutl[tid] = __logf((float)(tid < 1 ? 1 : tid));
  {
    const int i = tid >> 2, p = tid & 3;
    const int qi = g_sidx[base + s0 + i];
    if (p == 0) { qi_s[i] = qi; qh_s[i] = g_shash[base + s0 + i]; }
    const uint4* src = (const uint4*)(g_fqb + ((size_t)bh * L4 + qi) * DK);
    *(uint4*)&Qb[i][p * 16]     = src[2 * p];
    *(uint4*)&Qb[i][p * 16 + 8] = src[2 * p + 1];
    if (use_cnt) {
      const uint4* cs = (const uint4*)(g_cnt + ((size_t)bh * L4 + qi) * WIN);
      *(uint4*)&cnt8[i][p * 32]      = cs[2 * p];
      *(uint4*)&cnt8[i][p * 32 + 16] = cs[2 * p + 1];
    }
  }
  {
    const int j = tid >> 1, h = tid & 1;
    const bool pad = (c == 0) && (j < 64);
    if (pad) {
      if (h == 0) { ki_s[j] = -1; kh_s[j] = (1 << 30); }
      const uint4 z = make_uint4(0, 0, 0, 0);
      #pragma unroll
      for (int u = 0; u < 4; ++u) *(uint4*)&Kb[j][h * 32 + u * 8] = z;
    } else {
      const int ki = g_sidx[base + s0 - 64 + j];
      if (h == 0) { ki_s[j] = ki; kh_s[j] = g_shash[base + s0 - 64 + j]; }
      const uint4* src = (const uint4*)(g_fqb + ((size_t)bh * L4 + ki) * DK);
      #pragma unroll
      for (int u = 0; u < 4; ++u) *(uint4*)&Kb[j][h * 32 + u * 8] = src[h * 4 + u];
    }
  }
  __syncthreads();
  const int lane = tid & 63, w = tid >> 6;
  const int i0 = w * 16;
  const int li = lane & 15, lq = lane >> 4;
  v4f acc[8];
  #pragma unroll
  for (int jt = 0; jt < 8; ++jt) acc[jt] = (v4f){0.f, 0.f, 0.f, 0.f};
  #pragma unroll
  for (int ks = 0; ks < 2; ++ks) {
    const v8s aq = *(const v8s*)&Qb[i0 + li][ks * 32 + lq * 8];
    #pragma unroll
    for (int jt = 0; jt < 8; ++jt) {
      const v8s bk = *(const v8s*)&Kb[jt * 16 + li][ks * 32 + lq * 8];
      acc[jt] = __builtin_amdgcn_mfma_f32_16x16x32_bf16(aq, bk, acc[jt], 0, 0, 0);
    }
  }
  // masks (exact ordering), then per-row max / sumexp
  float mrow[4];
  #pragma unroll
  for (int reg = 0; reg < 4; ++reg) {
    const int i = i0 + lq * 4 + reg;
    const int qi = qi_s[i], qh = qh_s[i];
    float lm = -3.0f * BIGF;
    #pragma unroll
    for (int jt = 0; jt < 8; ++jt) {
      const int j = jt * 16 + li;
      const int ki = ki_s[j], kh = kh_s[j];
      float s;
      if (ki < 0) {
        s = 0.f - BIGF - BIGF - BIGF;
      } else {
        s = acc[jt][reg] * 0.125f;
        if (qh != kh) s -= BIGF;
        if (qi < ki)  s -= BIGF;
        if (qi == ki) s -= 100000.0f;
        if (use_cnt) s -= lutl[(cnt8[i][j] >> cnt_sh) & cnt_msk];
      }
      acc[jt][reg] = s;
      lm = fmaxf(lm, s);
    }
    #pragma unroll
    for (int off = 1; off < 16; off <<= 1) lm = fmaxf(lm, __shfl_xor(lm, off));
    mrow[reg] = lm;
    float ps = 0.f;
    #pragma unroll
    for (int jt = 0; jt < 8; ++jt) ps += __expf(acc[jt][reg] - lm);
    #pragma unroll
    for (int off = 1; off < 16; off <<= 1) ps += __shfl_xor(ps, off);
    if (li == 0) g_stat[base + s0 + i] = make_float2(lm, ps);
  }
  __syncthreads();   // all waves done reading Qb/Kb/cnt8; reuse as Pt|Vt
  #pragma unroll
  for (int reg = 0; reg < 4; ++reg) {
    const int i = i0 + lq * 4 + reg;
    #pragma unroll
    for (int jt = 0; jt < 8; ++jt)
      Pt[i][jt * 16 + li] = f2bf(__expf(acc[jt][reg] - mrow[reg]));
  }
  // V gather, transposed into LDS: Vt[d][j]
  {
    const int j = tid >> 1, h = tid & 1;
    const bool pad = (c == 0) && (j < 64);
    if (pad) {
      #pragma unroll
      for (int d = 0; d < 32; ++d) Vt[h * 32 + d][j] = 0;
    } else {
      const int ki = g_sidx[base + s0 - 64 + j];
      const uint4* src = (const uint4*)(g_fvb + ((size_t)bh * L4 + ki) * DK);
      #pragma unroll
      for (int u = 0; u < 4; ++u) {
        const uint4 v = src[h * 4 + u];
        const unsigned short* e = (const unsigned short*)&v;
        #pragma unroll
        for (int t = 0; t < 8; ++t) Vt[h * 32 + u * 8 + t][j] = e[t];
      }
    }
  }
  __syncthreads();
  // PV MFMA; write UNNORMALIZED O' (scale deferred to combine)
  v4f acc2[4];
  #pragma unroll
  for (int dt = 0; dt < 4; ++dt) acc2[dt] = (v4f){0.f, 0.f, 0.f, 0.f};
  #pragma unroll
  for (int ks = 0; ks < 4; ++ks) {
    const v8s pa = *(const v8s*)&Pt[i0 + li][ks * 32 + lq * 8];
    #pragma unroll
    for (int dt = 0; dt < 4; ++dt) {
      const v8s vb = *(const v8s*)&Vt[dt * 16 + li][ks * 32 + lq * 8];
      acc2[dt] = __builtin_amdgcn_mfma_f32_16x16x32_bf16(pa, vb, acc2[dt], 0, 0, 0);
    }
  }
  #pragma unroll
  for (int reg = 0; reg < 4; ++reg) {
    const int i = i0 + lq * 4 + reg;
    unsigned short* orow = g_osortb + ((size_t)(base + s0 + i)) * DK;
    #pragma unroll
    for (int dt = 0; dt < 4; ++dt)
      orow[dt * 16 + li] = f2bf(acc2[dt][reg]);
  }
}

// ---- merge per-round stats at each original row: (M, 1/Z) for the joint softmax ----
__global__ __launch_bounds__(256) void merge_kernel() {
  const int idx = blockIdx.x * 256 + threadIdx.x;  // bh*L4 + l
  const int bh = idx >> 12, l = idx & (L4 - 1);
  float m[4], z[4];
  #pragma unroll
  for (int r = 0; r < NR; ++r) {
    const int base = (bh * NR + r) * L4;
    const int spos = g_inv[base + l];
    const float2 st = g_stat[base + spos];
    m[r] = st.x; z[r] = st.y;
  }
  const float M = fmaxf(fmaxf(m[0], m[1]), fmaxf(m[2], m[3]));
  const float Z = z[0] * __expf(m[0] - M) + z[1] * __expf(m[1] - M)
                + z[2] * __expf(m[2] - M) + z[3] * __expf(m[3] - M);
  g_MZ[idx] = make_float2(M, 1.0f / Z);
}

// ------- gather per-round UNNORMALIZED outputs, apply scale_r, sum rounds -------
__global__ __launch_bounds__(256) void combine_kernel() {
  const int b = blockIdx.x >> 12, l = blockIdx.x & (L4 - 1);
  const int tid = threadIdx.x;
  const int d = tid & 63, h0 = tid >> 6;
  #pragma unroll
  for (int hh = h0; hh < 8; hh += 4) {
    const int bh = b * 8 + hh;
    const float2 mz = g_MZ[(size_t)bh * L4 + l];
    float v = 0.f;
    #pragma unroll
    for (int r = 0; r < NR; ++r) {
      const int base = (bh * NR + r) * L4;
      const int s = g_inv[base + l];
      const float m_r = g_stat[base + s].x;
      const float scale = __expf(m_r - mz.x) * mz.y;
      v += bf2f(g_osortb[((size_t)base + s) * DK + d]) * scale;
    }
    g_xb[((size_t)b * L4 + l) * DM + hh * 64 + d] = f2bf(v);
  }
}

// -------- bf16 MFMA GEMM: out = g_xb @ Wo^T + bo ; N-tile 128 (A re-read 4x not 8x) --------
__global__ __launch_bounds__(256) void mgemm2(const float* __restrict__ W,
                                              const float* __restrict__ bias,
                                              float* __restrict__ outp)
{
  const int m0 = blockIdx.x * 128;
  const int n0 = blockIdx.y * 128;
  __shared__ unsigned short As[128][72];
  __shared__ unsigned short Bs[128][72];
  const int tid = threadIdx.x;
  const int lane = tid & 63, w = tid >> 6;
  const int li = lane & 15, lq = lane >> 4;
  v4f acc[2][8];
  #pragma unroll
  for (int mt = 0; mt < 2; ++mt)
    #pragma unroll
    for (int jt = 0; jt < 8; ++jt) acc[mt][jt] = (v4f){0.f, 0.f, 0.f, 0.f};
  for (int kt = 0; kt < DM; kt += 64) {
    __syncthreads();
    {
      const int row = tid >> 1, h = tid & 1;
      const unsigned short* src = g_xb + (size_t)(m0 + row) * DM + kt + h * 32;
      #pragma unroll
      for (int u = 0; u < 4; ++u)
        *(uint4*)&As[row][h * 32 + u * 8] = ((const uint4*)src)[u];
    }
    {
      const int row = tid >> 1, h = tid & 1;
      const float* src = W + (size_t)(n0 + row) * DM + kt + h * 32;
      #pragma unroll
      for (int u = 0; u < 4; ++u) {
        const float4 x = *(const float4*)(src + u * 8);
        const float4 y = *(const float4*)(src + u * 8 + 4);
        *(ushort4*)&Bs[row][h * 32 + u * 8]     = f2bf4(x);
        *(ushort4*)&Bs[row][h * 32 + u * 8 + 4] = f2bf4(y);
      }
    }
    __syncthreads();
    #pragma unroll
    for (int ks = 0; ks < 2; ++ks) {
      const v8s aq0 = *(const v8s*)&As[w * 32 + li][ks * 32 + lq * 8];
      const v8s aq1 = *(const v8s*)&As[w * 32 + 16 + li][ks * 32 + lq * 8];
      #pragma unroll
      for (int jt = 0; jt < 8; ++jt) {
        const v8s bk = *(const v8s*)&Bs[jt * 16 + li][ks * 32 + lq * 8];
        acc[0][jt] = __builtin_amdgcn_mfma_f32_16x16x32_bf16(aq0, bk, acc[0][jt], 0, 0, 0);
        acc[1][jt] = __builtin_amdgcn_mfma_f32_16x16x32_bf16(aq1, bk, acc[1][jt], 0, 0, 0);
      }
    }
  }
  #pragma unroll
  for (int mt = 0; mt < 2; ++mt)
    #pragma unroll
    for (int jt = 0; jt < 8; ++jt)
      #pragma unroll
      for (int reg = 0; reg < 4; ++reg) {
        const int m = m0 + w * 32 + mt * 16 + lq * 4 + reg;
        const int n = n0 + jt * 16 + li;
        outp[(size_t)m * DM + n] = acc[mt][jt][reg] + bias[n];
      }
}

extern "C" void kernel_launch(void* const* d_in, const int* in_sizes, int n_in,
                              void* d_out, int out_size, void* d_ws, size_t ws_size,
                              hipStream_t stream) {
  (void)in_sizes; (void)n_in; (void)d_ws; (void)ws_size; (void)out_size;
  const float* query = (const float*)d_in[0];
  const float* value = (const float*)d_in[1];
  // d_in[2] = mask: all-true; its effect (look-back pad masking) is explicit.
  const float* Wq = (const float*)d_in[3];
  const float* bq = (const float*)d_in[4];
  const float* Wv = (const float*)d_in[5];
  const float* bv = (const float*)d_in[6];
  const float* Wo = (const float*)d_in[7];
  const float* bo = (const float*)d_in[8];
  const float* rm = (const float*)d_in[9];
  float* out = (float*)d_out;

  stage1_kernel<<<1088, 256, 0, stream>>>(query, Wq, bq, value, Wv, bv, rm);
  hash_kernel<<<1024, 256, 0, stream>>>();
  sort_kernel<<<64, 128, 0, stream>>>();
  counts_kernel<<<dim3(16, 128), 256, 0, stream>>>();
  passA_kernel<<<dim3(64, 4, 16), 256, 0, stream>>>();
  merge_kernel<<<256, 256, 0, stream>>>();
  combine_kernel<<<8192, 256, 0, stream>>>();
  mgemm2<<<dim3(64, 4), 256, 0, stream>>>(Wo, bo, out);
}

// Round 16
// 261.387 us; speedup vs baseline: 1.0297x; 1.0297x over previous
//
#include <hip/hip_runtime.h>

// Problem constants: B=2, L=4096, D_MODEL=512, HEAD=8, D_K=64,
// N_BUCKETS=128, ROUNDS=4, 64 chunks of 64 sorted positions, window=128.
#define L4   4096
#define DK   64
#define NR   4
#define NB   128
#define WIN  128
#define DM   512
#define BH   16
#define BIGF 1000000000.0f

typedef short v8s __attribute__((ext_vector_type(8)));
typedef float v4f __attribute__((ext_vector_type(4)));

__device__ __forceinline__ unsigned short f2bf(float x) {
  union { float f; unsigned u; } v; v.f = x;
  const unsigned r = (v.u + 0x7FFFu + ((v.u >> 16) & 1u)) >> 16;
  return (unsigned short)r;
}
__device__ __forceinline__ float bf2f(unsigned short u) {
  union { unsigned u; float f; } v; v.u = ((unsigned)u) << 16;
  return v.f;
}
__device__ __forceinline__ ushort4 f2bf4(const float4 x) {
  ushort4 r; r.x = f2bf(x.x); r.y = f2bf(x.y); r.z = f2bf(x.z); r.w = f2bf(x.w);
  return r;
}

// ---- static device workspace (deterministic, fully rewritten per call) ----
__device__ float g_fqn[(size_t)BH * L4 * DK];            // normalized q f32 (hash path)
__device__ unsigned short g_fqb[(size_t)BH * L4 * DK];   // normalized q bf16 (scores)
__device__ unsigned short g_fvb[(size_t)BH * L4 * DK];   // v bf16 (PV)
__device__ float g_rmnT[NR * 64 * DK];                   // normalized rand matrix [r][k][d]
__device__ int   g_hash [BH * NR * L4];
__device__ int   g_sidx [BH * NR * L4];                  // sorted pos -> original l
__device__ int   g_shash[BH * NR * L4];
__device__ int   g_inv  [BH * NR * L4];                  // original l -> sorted pos
__device__ unsigned char g_cnt[(size_t)BH * L4 * WIN];   // packed dup-key counts: n0|n1<<3|n2<<6
__device__ float2 g_stat[BH * NR * L4];                  // per-round row (max, sumexp) by spos
__device__ unsigned short g_osortb[(size_t)BH * NR * L4 * DK]; // UNNORMALIZED per-round out bf16, sorted
__device__ unsigned short g_xb[(size_t)2 * L4 * DM];     // concat-head attention out (bf16)

// ===== stage 1 (R10 best-known structure, exact): range-split
// blocks [0,512): qproj | [512,1024): V-proj MFMA | [1024,1088): rmnorm
__global__ __launch_bounds__(256) void stage1_kernel(const float* __restrict__ A,
                                                     const float* __restrict__ Wq,
                                                     const float* __restrict__ bq,
                                                     const float* __restrict__ Vf,
                                                     const float* __restrict__ Wv,
                                                     const float* __restrict__ bv,
                                                     const float* __restrict__ rm)
{
  __shared__ __align__(16) char smem[27648];
  const int bid = blockIdx.x;
  const int tid = threadIdx.x;
  if (bid < 512) {
    // ---------------- qproj body (R9/R10 passing version) ----------------
    float (*As)[132] = (float(*)[132])smem;                 // 16896 B
    float (*Bs)[68]  = (float(*)[68])(smem + 16896);        //  8704 B
    const int m0 = (bid & 63) * 128;
    const int n0 = (bid >> 6) * 64;
    const int am = tid & 127, ak0 = (tid >> 7) * 16;
    const int bn = tid & 63,  bk0 = (tid >> 6) * 8;
    const float* arow = A + (size_t)(m0 + am) * DM + ak0;
    const float* brow = Wq + (size_t)(n0 + bn) * DM + bk0;
    float4 pa0 = *(const float4*)(arow);
    float4 pa1 = *(const float4*)(arow + 4);
    float4 pa2 = *(const float4*)(arow + 8);
    float4 pa3 = *(const float4*)(arow + 12);
    float4 pb0 = *(const float4*)(brow);
    float4 pb1 = *(const float4*)(brow + 4);
    const int lane = tid & 63, w = tid >> 6;
    const int ng = lane & 15, mgl = lane >> 4;
    const int mbase = (w * 4 + mgl) * 8;
    const int nbase = ng * 4;
    float acc[8][4] = {};
    for (int kt = 0; kt < DM; kt += 32) {
      __syncthreads();
      As[ak0 +  0][am] = pa0.x; As[ak0 +  1][am] = pa0.y; As[ak0 +  2][am] = pa0.z; As[ak0 +  3][am] = pa0.w;
      As[ak0 +  4][am] = pa1.x; As[ak0 +  5][am] = pa1.y; As[ak0 +  6][am] = pa1.z; As[ak0 +  7][am] = pa1.w;
      As[ak0 +  8][am] = pa2.x; As[ak0 +  9][am] = pa2.y; As[ak0 + 10][am] = pa2.z; As[ak0 + 11][am] = pa2.w;
      As[ak0 + 12][am] = pa3.x; As[ak0 + 13][am] = pa3.y; As[ak0 + 14][am] = pa3.z; As[ak0 + 15][am] = pa3.w;
      Bs[bk0 + 0][bn] = pb0.x; Bs[bk0 + 1][bn] = pb0.y; Bs[bk0 + 2][bn] = pb0.z; Bs[bk0 + 3][bn] = pb0.w;
      Bs[bk0 + 4][bn] = pb1.x; Bs[bk0 + 5][bn] = pb1.y; Bs[bk0 + 6][bn] = pb1.z; Bs[bk0 + 7][bn] = pb1.w;
      __syncthreads();
      if (kt + 32 < DM) {
        pa0 = *(const float4*)(arow + kt + 32);
        pa1 = *(const float4*)(arow + kt + 36);
        pa2 = *(const float4*)(arow + kt + 40);
        pa3 = *(const float4*)(arow + kt + 44);
        pb0 = *(const float4*)(brow + kt + 32);
        pb1 = *(const float4*)(brow + kt + 36);
      }
      #pragma unroll
      for (int kk = 0; kk < 32; ++kk) {
        const float4 a0 = *(const float4*)&As[kk][mbase];
        const float4 a1 = *(const float4*)&As[kk][mbase + 4];
        const float4 bv4 = *(const float4*)&Bs[kk][nbase];
        const float amv[8] = {a0.x, a0.y, a0.z, a0.w, a1.x, a1.y, a1.z, a1.w};
        const float bnv[4] = {bv4.x, bv4.y, bv4.z, bv4.w};
        #pragma unroll
        for (int i = 0; i < 8; ++i)
          #pragma unroll
          for (int j = 0; j < 4; ++j)
            acc[i][j] = fmaf(amv[i], bnv[j], acc[i][j]);
      }
    }
    #pragma unroll
    for (int j = 0; j < 4; ++j) {
      const float bb = bq[n0 + nbase + j];
      #pragma unroll
      for (int i = 0; i < 8; ++i) acc[i][j] += bb;
    }
    float sc[8];
    #pragma unroll
    for (int i = 0; i < 8; ++i) {
      float s = acc[i][0] * acc[i][0];
      s = fmaf(acc[i][1], acc[i][1], s);
      s = fmaf(acc[i][2], acc[i][2], s);
      s = fmaf(acc[i][3], acc[i][3], s);
      s += __shfl_xor(s, 1);
      s += __shfl_xor(s, 2);
      s += __shfl_xor(s, 4);
      s += __shfl_xor(s, 8);
      sc[i] = 1.0f / sqrtf(s);
    }
    const int bh = (m0 >> 12) * 8 + (n0 >> 6);
    const int lb = (m0 & (L4 - 1)) + mbase;
    #pragma unroll
    for (int i = 0; i < 8; ++i) {
      const size_t idx = ((size_t)bh * L4 + lb + i) * DK + nbase;
      float4 o;
      o.x = acc[i][0] * sc[i]; o.y = acc[i][1] * sc[i];
      o.z = acc[i][2] * sc[i]; o.w = acc[i][3] * sc[i];
      *(float4*)(g_fqn + idx) = o;
      *(ushort4*)(g_fqb + idx) = f2bf4(o);
    }
  } else if (bid < 1024) {
    // ------------- V projection, bf16 MFMA (unchanged body) -------------
    unsigned short (*As)[72] = (unsigned short(*)[72])smem;          // 18432 B
    unsigned short (*Bs)[72] = (unsigned short(*)[72])(smem + 18432); //  9216 B
    const int b2 = bid - 512;
    const int m0 = (b2 & 63) * 128;
    const int n0 = (b2 >> 6) * 64;
    const int lane = tid & 63, w = tid >> 6;
    const int li = lane & 15, lq = lane >> 4;
    v4f acc[2][4];
    #pragma unroll
    for (int mt = 0; mt < 2; ++mt)
      #pragma unroll
      for (int jt = 0; jt < 4; ++jt) acc[mt][jt] = (v4f){0.f, 0.f, 0.f, 0.f};
    for (int kt = 0; kt < DM; kt += 64) {
      __syncthreads();
      {
        const int row = tid >> 1, h = tid & 1;
        const float* src = Vf + (size_t)(m0 + row) * DM + kt + h * 32;
        #pragma unroll
        for (int u = 0; u < 4; ++u) {
          const float4 x = *(const float4*)(src + u * 8);
          const float4 y = *(const float4*)(src + u * 8 + 4);
          *(ushort4*)&As[row][h * 32 + u * 8]     = f2bf4(x);
          *(ushort4*)&As[row][h * 32 + u * 8 + 4] = f2bf4(y);
        }
      }
      {
        const int row = tid >> 2, p = tid & 3;
        const float* src = Wv + (size_t)(n0 + row) * DM + kt + p * 16;
        #pragma unroll
        for (int u = 0; u < 2; ++u) {
          const float4 x = *(const float4*)(src + u * 8);
          const float4 y = *(const float4*)(src + u * 8 + 4);
          *(ushort4*)&Bs[row][p * 16 + u * 8]     = f2bf4(x);
          *(ushort4*)&Bs[row][p * 16 + u * 8 + 4] = f2bf4(y);
        }
      }
      __syncthreads();
      #pragma unroll
      for (int ks = 0; ks < 2; ++ks) {
        const v8s aq0 = *(const v8s*)&As[w * 32 + li][ks * 32 + lq * 8];
        const v8s aq1 = *(const v8s*)&As[w * 32 + 16 + li][ks * 32 + lq * 8];
        #pragma unroll
        for (int jt = 0; jt < 4; ++jt) {
          const v8s bk = *(const v8s*)&Bs[jt * 16 + li][ks * 32 + lq * 8];
          acc[0][jt] = __builtin_amdgcn_mfma_f32_16x16x32_bf16(aq0, bk, acc[0][jt], 0, 0, 0);
          acc[1][jt] = __builtin_amdgcn_mfma_f32_16x16x32_bf16(aq1, bk, acc[1][jt], 0, 0, 0);
        }
      }
    }
    #pragma unroll
    for (int mt = 0; mt < 2; ++mt)
      #pragma unroll
      for (int jt = 0; jt < 4; ++jt)
        #pragma unroll
        for (int reg = 0; reg < 4; ++reg) {
          const int m = m0 + w * 32 + mt * 16 + lq * 4 + reg;
          const int n = n0 + jt * 16 + li;
          const float vv = acc[mt][jt][reg] + bv[n];
          const int bh = (m >> 12) * 8 + (n >> 6);
          const int l = m & (L4 - 1);
          g_fvb[((size_t)bh * L4 + l) * DK + (n & 63)] = f2bf(vv);
        }
  } else {
    // --- rmnorm body (4 rows/block) ---
    const int dr = (bid - 1024) * 4 + (tid >> 6);   // d*4 + r
    const int k = tid & 63;
    const float v = rm[dr * 64 + k];
    float s = v * v;
    #pragma unroll
    for (int off = 32; off; off >>= 1) s += __shfl_xor(s, off);
    const int d = dr >> 2, r = dr & 3;
    g_rmnT[(r * 64 + k) * DK + d] = v / sqrtf(s);
  }
}

// --------- hash: proj = fqn . rmn, argmax over [proj, -proj] (first index) ---------
__global__ __launch_bounds__(256, 4) void hash_kernel() {
  const int tid = threadIdx.x;
  const int w = __builtin_amdgcn_readfirstlane(tid >> 6);   // round (wave-uniform)
  const int lane = tid & 63;          // row within group
  const int row = blockIdx.x * 64 + lane;   // flattened bh*L4 + l
  float q[64];
  #pragma unroll
  for (int du = 0; du < 16; ++du) {
    const float4 v = *(const float4*)(g_fqn + (size_t)row * DK + du * 4);
    q[du * 4 + 0] = v.x; q[du * 4 + 1] = v.y;
    q[du * 4 + 2] = v.z; q[du * 4 + 3] = v.w;
  }
  const float* rmw = g_rmnT + w * (64 * DK);
  float bestP = -BIGF, bestN = -BIGF;
  int idxP = 0, idxN = 0;
  for (int k = 0; k < 64; k += 2) {
    const float* rp0 = rmw + k * DK;        // wave-uniform -> s_load
    const float* rp1 = rp0 + DK;
    float a0 = 0.f, a1 = 0.f;
    #pragma unroll
    for (int d = 0; d < 64; ++d) {
      a0 = fmaf(q[d], rp0[d], a0);
      a1 = fmaf(q[d], rp1[d], a1);
    }
    if (a0 > bestP)  { bestP = a0;  idxP = k; }
    if (-a0 > bestN) { bestN = -a0; idxN = k; }
    if (a1 > bestP)  { bestP = a1;  idxP = k + 1; }
    if (-a1 > bestN) { bestN = -a1; idxN = k + 1; }
  }
  const int idx = (bestP >= bestN) ? idxP : 64 + idxN;
  const int bh = row >> 12, l = row & (L4 - 1);
  g_hash[(bh * NR + w) * L4 + l] = idx;
}

// ------------- stable counting sort of 4096 hashes per (bh, round) -------------
__global__ __launch_bounds__(128) void sort_kernel() {
  __shared__ int chunkHist[64][NB];   // 32 KB
  __shared__ int tot[NB];
  __shared__ int binBase[NB];
  const int bhr = blockIdx.x;         // bh*4 + r
  const int t = threadIdx.x;
  const int* hrow = g_hash + bhr * L4;
  for (int idx = t; idx < 64 * NB; idx += 128) ((int*)chunkHist)[idx] = 0;
  __syncthreads();
  if (t < 64) {
    for (int e = 0; e < 64; ++e) chunkHist[t][hrow[t * 64 + e]]++;
  }
  __syncthreads();
  if (t < NB) { int s = 0; for (int cc = 0; cc < 64; ++cc) s += chunkHist[cc][t]; tot[t] = s; }
  __syncthreads();
  if (t == 0) { int run = 0; for (int h = 0; h < NB; ++h) { binBase[h] = run; run += tot[h]; } }
  __syncthreads();
  if (t < NB) {
    int run = binBase[t];
    for (int cc = 0; cc < 64; ++cc) { const int tmp = chunkHist[cc][t]; chunkHist[cc][t] = run; run += tmp; }
  }
  __syncthreads();
  if (t < 64) {
    for (int e = 0; e < 64; ++e) {
      const int l = t * 64 + e;
      const int h = hrow[l];
      const int p = chunkHist[t][h]++;
      g_sidx [bhr * L4 + p] = l;
      g_shash[bhr * L4 + p] = h;
      g_inv  [bhr * L4 + l] = p;
    }
  }
}

// ---- duplicate-key counts (bug-faithful), PACKED: n0 | n1<<3 | n2<<6 per byte ----
__global__ __launch_bounds__(256) void counts_kernel() {
  const int bh = blockIdx.x;
  const int l0 = blockIdx.y * 32;
  const int j = threadIdx.x & 127;
  const int lh = threadIdx.x >> 7;   // 0..1
  for (int u = 0; u < 16; ++u) {
    const int l = l0 + u * 2 + lh;
    int a[4];
    #pragma unroll
    for (int r = 0; r < NR; ++r) {
      const int base = (bh * NR + r) * L4;
      const int spos = g_inv[base + l];
      const int c = spos >> 6;
      // shared pad sentinel across rounds (reference's 1e9==1e9 pad equality)
      a[r] = (c == 0 && j < 64) ? (1 << 20) : g_sidx[base + c * 64 - 64 + j];
    }
    const int c01 = a[0] == a[1], c02 = a[0] == a[2], c03 = a[0] == a[3];
    const int c12 = a[1] == a[2], c13 = a[1] == a[3], c23 = a[2] == a[3];
    const int n0 = 1 + 2 * c01 + c02 + c03 + c12 + c23;
    const int n1 = 1 + c02 + c12 + 2 * c13;
    const int n2 = 1 + c03 + c23;
    g_cnt[((size_t)bh * L4 + l) * WIN + j] = (unsigned char)(n0 | (n1 << 3) | (n2 << 6));
  }
}

// ==== fused attention pass: MFMA QK^T + masks -> (m, Z) stat -> P'=exp(s-m) bf16
// in LDS -> V gather -> PV MFMA -> UNNORMALIZED O' bf16 to g_osortb.
// Grid is flattened 1D with an XCD-chunk swizzle: consecutive c chunks share 50%
// of their K/V window rows; giving each XCD a contiguous (c,r,bh) span makes the
// overlap re-reads hit the same XCD's L2 (T1; bijective since 4096 % 8 == 0).
__global__ __launch_bounds__(256) void passA_kernel() {
  const int flat = (blockIdx.x & 7) * 512 + (blockIdx.x >> 3);
  const int c = flat & 63, r = (flat >> 6) & 3, bh = flat >> 8;
  const int base = (bh * NR + r) * L4;
  const int s0 = c * 64;
  const bool use_cnt = (r != 3);   // round-3 counts are identically 1
  const int cnt_sh = (r == 2) ? 6 : r * 3;    // block-uniform unpack shift
  const int cnt_msk = (r == 2) ? 3 : 7;
  __shared__ __align__(16) char smem[35840];
  unsigned short (*Qb)[72] = (unsigned short(*)[72])smem;            //  9216 B
  unsigned short (*Kb)[72] = (unsigned short(*)[72])(smem + 9216);   // 18432 B
  unsigned char (*cnt8)[128] = (unsigned char(*)[128])(smem + 27648); // 8192 B
  unsigned short (*Pt)[136] = (unsigned short(*)[136])smem;          // 17408 B (phase 2)
  unsigned short (*Vt)[136] = (unsigned short(*)[136])(smem + 17408); // 17408 B (phase 2)
  __shared__ int qi_s[64], qh_s[64], ki_s[128], kh_s[128];
  __shared__ float lutl[9];
  const int tid = threadIdx.x;
  if (tid < 9) lutl[tid] = __logf((float)(tid < 1 ? 1 : tid));
  {
    const int i = tid >> 2, p = tid & 3;
    const int qi = g_sidx[base + s0 + i];
    if (p == 0) { qi_s[i] = qi; qh_s[i] = g_shash[base + s0 + i]; }
    const uint4* src = (const uint4*)(g_fqb + ((size_t)bh * L4 + qi) * DK);
    *(uint4*)&Qb[i][p * 16]     = src[2 * p];
    *(uint4*)&Qb[i][p * 16 + 8] = src[2 * p + 1];
    if (use_cnt) {
      const uint4* cs = (const uint4*)(g_cnt + ((size_t)bh * L4 + qi) * WIN);
      *(uint4*)&cnt8[i][p * 32]      = cs[2 * p];
      *(uint4*)&cnt8[i][p * 32 + 16] = cs[2 * p + 1];
    }
  }
  {
    const int j = tid >> 1, h = tid & 1;
    const bool pad = (c == 0) && (j < 64);
    if (pad) {
      if (h == 0) { ki_s[j] = -1; kh_s[j] = (1 << 30); }
      const uint4 z = make_uint4(0, 0, 0, 0);
      #pragma unroll
      for (int u = 0; u < 4; ++u) *(uint4*)&Kb[j][h * 32 + u * 8] = z;
    } else {
      const int ki = g_sidx[base + s0 - 64 + j];
      if (h == 0) { ki_s[j] = ki; kh_s[j] = g_shash[base + s0 - 64 + j]; }
      const uint4* src = (const uint4*)(g_fqb + ((size_t)bh * L4 + ki) * DK);
      #pragma unroll
      for (int u = 0; u < 4; ++u) *(uint4*)&Kb[j][h * 32 + u * 8] = src[h * 4 + u];
    }
  }
  __syncthreads();
  const int lane = tid & 63, w = tid >> 6;
  const int i0 = w * 16;
  const int li = lane & 15, lq = lane >> 4;
  v4f acc[8];
  #pragma unroll
  for (int jt = 0; jt < 8; ++jt) acc[jt] = (v4f){0.f, 0.f, 0.f, 0.f};
  #pragma unroll
  for (int ks = 0; ks < 2; ++ks) {
    const v8s aq = *(const v8s*)&Qb[i0 + li][ks * 32 + lq * 8];
    #pragma unroll
    for (int jt = 0; jt < 8; ++jt) {
      const v8s bk = *(const v8s*)&Kb[jt * 16 + li][ks * 32 + lq * 8];
      acc[jt] = __builtin_amdgcn_mfma_f32_16x16x32_bf16(aq, bk, acc[jt], 0, 0, 0);
    }
  }
  // masks (exact ordering), then per-row max / sumexp
  float mrow[4];
  #pragma unroll
  for (int reg = 0; reg < 4; ++reg) {
    const int i = i0 + lq * 4 + reg;
    const int qi = qi_s[i], qh = qh_s[i];
    float lm = -3.0f * BIGF;
    #pragma unroll
    for (int jt = 0; jt < 8; ++jt) {
      const int j = jt * 16 + li;
      const int ki = ki_s[j], kh = kh_s[j];
      float s;
      if (ki < 0) {
        s = 0.f - BIGF - BIGF - BIGF;
      } else {
        s = acc[jt][reg] * 0.125f;
        if (qh != kh) s -= BIGF;
        if (qi < ki)  s -= BIGF;
        if (qi == ki) s -= 100000.0f;
        if (use_cnt) s -= lutl[(cnt8[i][j] >> cnt_sh) & cnt_msk];
      }
      acc[jt][reg] = s;
      lm = fmaxf(lm, s);
    }
    #pragma unroll
    for (int off = 1; off < 16; off <<= 1) lm = fmaxf(lm, __shfl_xor(lm, off));
    mrow[reg] = lm;
    float ps = 0.f;
    #pragma unroll
    for (int jt = 0; jt < 8; ++jt) ps += __expf(acc[jt][reg] - lm);
    #pragma unroll
    for (int off = 1; off < 16; off <<= 1) ps += __shfl_xor(ps, off);
    if (li == 0) g_stat[base + s0 + i] = make_float2(lm, ps);
  }
  __syncthreads();   // all waves done reading Qb/Kb/cnt8; reuse as Pt|Vt
  #pragma unroll
  for (int reg = 0; reg < 4; ++reg) {
    const int i = i0 + lq * 4 + reg;
    #pragma unroll
    for (int jt = 0; jt < 8; ++jt)
      Pt[i][jt * 16 + li] = f2bf(__expf(acc[jt][reg] - mrow[reg]));
  }
  // V gather, transposed into LDS: Vt[d][j]
  {
    const int j = tid >> 1, h = tid & 1;
    const bool pad = (c == 0) && (j < 64);
    if (pad) {
      #pragma unroll
      for (int d = 0; d < 32; ++d) Vt[h * 32 + d][j] = 0;
    } else {
      const int ki = g_sidx[base + s0 - 64 + j];
      const uint4* src = (const uint4*)(g_fvb + ((size_t)bh * L4 + ki) * DK);
      #pragma unroll
      for (int u = 0; u < 4; ++u) {
        const uint4 v = src[h * 4 + u];
        const unsigned short* e = (const unsigned short*)&v;
        #pragma unroll
        for (int t = 0; t < 8; ++t) Vt[h * 32 + u * 8 + t][j] = e[t];
      }
    }
  }
  __syncthreads();
  // PV MFMA; write UNNORMALIZED O' (scale deferred to combine)
  v4f acc2[4];
  #pragma unroll
  for (int dt = 0; dt < 4; ++dt) acc2[dt] = (v4f){0.f, 0.f, 0.f, 0.f};
  #pragma unroll
  for (int ks = 0; ks < 4; ++ks) {
    const v8s pa = *(const v8s*)&Pt[i0 + li][ks * 32 + lq * 8];
    #pragma unroll
    for (int dt = 0; dt < 4; ++dt) {
      const v8s vb = *(const v8s*)&Vt[dt * 16 + li][ks * 32 + lq * 8];
      acc2[dt] = __builtin_amdgcn_mfma_f32_16x16x32_bf16(pa, vb, acc2[dt], 0, 0, 0);
    }
  }
  #pragma unroll
  for (int reg = 0; reg < 4; ++reg) {
    const int i = i0 + lq * 4 + reg;
    unsigned short* orow = g_osortb + ((size_t)(base + s0 + i)) * DK;
    #pragma unroll
    for (int dt = 0; dt < 4; ++dt)
      orow[dt * 16 + li] = f2bf(acc2[dt][reg]);
  }
}

// ------- gather per-round UNNORMALIZED outputs; inline softmax merge; sum rounds -------
// merge_kernel folded in: M = max m_r, Z = sum z_r * exp(m_r - M) computed from the
// same g_stat float2 loads (identical f32 op order as the old merge), then
// scale_r = exp(m_r - M) / Z applied per round.
__global__ __launch_bounds__(256) void combine_kernel() {
  const int b = blockIdx.x >> 12, l = blockIdx.x & (L4 - 1);
  const int tid = threadIdx.x;
  const int d = tid & 63, h0 = tid >> 6;
  #pragma unroll
  for (int hh = h0; hh < 8; hh += 4) {
    const int bh = b * 8 + hh;
    int sidx[4];
    float m[4], z[4];
    #pragma unroll
    for (int r = 0; r < NR; ++r) {
      const int base = (bh * NR + r) * L4;
      const int s = g_inv[base + l];
      sidx[r] = s;
      const float2 st = g_stat[base + s];
      m[r] = st.x; z[r] = st.y;
    }
    const float M = fmaxf(fmaxf(m[0], m[1]), fmaxf(m[2], m[3]));
    const float Z = z[0] * __expf(m[0] - M) + z[1] * __expf(m[1] - M)
                  + z[2] * __expf(m[2] - M) + z[3] * __expf(m[3] - M);
    const float invZ = 1.0f / Z;
    float v = 0.f;
    #pragma unroll
    for (int r = 0; r < NR; ++r) {
      const int base = (bh * NR + r) * L4;
      const float scale = __expf(m[r] - M) * invZ;
      v += bf2f(g_osortb[((size_t)base + sidx[r]) * DK + d]) * scale;
    }
    g_xb[((size_t)b * L4 + l) * DM + hh * 64 + d] = f2bf(v);
  }
}

// -------- bf16 MFMA GEMM: out = g_xb @ Wo^T + bo ; N-tile 128 --------
__global__ __launch_bounds__(256) void mgemm2(const float* __restrict__ W,
                                              const float* __restrict__ bias,
                                              float* __restrict__ outp)
{
  const int m0 = blockIdx.x * 128;
  const int n0 = blockIdx.y * 128;
  __shared__ unsigned short As[128][72];
  __shared__ unsigned short Bs[128][72];
  const int tid = threadIdx.x;
  const int lane = tid & 63, w = tid >> 6;
  const int li = lane & 15, lq = lane >> 4;
  v4f acc[2][8];
  #pragma unroll
  for (int mt = 0; mt < 2; ++mt)
    #pragma unroll
    for (int jt = 0; jt < 8; ++jt) acc[mt][jt] = (v4f){0.f, 0.f, 0.f, 0.f};
  for (int kt = 0; kt < DM; kt += 64) {
    __syncthreads();
    {
      const int row = tid >> 1, h = tid & 1;
      const unsigned short* src = g_xb + (size_t)(m0 + row) * DM + kt + h * 32;
      #pragma unroll
      for (int u = 0; u < 4; ++u)
        *(uint4*)&As[row][h * 32 + u * 8] = ((const uint4*)src)[u];
    }
    {
      const int row = tid >> 1, h = tid & 1;
      const float* src = W + (size_t)(n0 + row) * DM + kt + h * 32;
      #pragma unroll
      for (int u = 0; u < 4; ++u) {
        const float4 x = *(const float4*)(src + u * 8);
        const float4 y = *(const float4*)(src + u * 8 + 4);
        *(ushort4*)&Bs[row][h * 32 + u * 8]     = f2bf4(x);
        *(ushort4*)&Bs[row][h * 32 + u * 8 + 4] = f2bf4(y);
      }
    }
    __syncthreads();
    #pragma unroll
    for (int ks = 0; ks < 2; ++ks) {
      const v8s aq0 = *(const v8s*)&As[w * 32 + li][ks * 32 + lq * 8];
      const v8s aq1 = *(const v8s*)&As[w * 32 + 16 + li][ks * 32 + lq * 8];
      #pragma unroll
      for (int jt = 0; jt < 8; ++jt) {
        const v8s bk = *(const v8s*)&Bs[jt * 16 + li][ks * 32 + lq * 8];
        acc[0][jt] = __builtin_amdgcn_mfma_f32_16x16x32_bf16(aq0, bk, acc[0][jt], 0, 0, 0);
        acc[1][jt] = __builtin_amdgcn_mfma_f32_16x16x32_bf16(aq1, bk, acc[1][jt], 0, 0, 0);
      }
    }
  }
  #pragma unroll
  for (int mt = 0; mt < 2; ++mt)
    #pragma unroll
    for (int jt = 0; jt < 8; ++jt)
      #pragma unroll
      for (int reg = 0; reg < 4; ++reg) {
        const int m = m0 + w * 32 + mt * 16 + lq * 4 + reg;
        const int n = n0 + jt * 16 + li;
        outp[(size_t)m * DM + n] = acc[mt][jt][reg] + bias[n];
      }
}

extern "C" void kernel_launch(void* const* d_in, const int* in_sizes, int n_in,
                              void* d_out, int out_size, void* d_ws, size_t ws_size,
                              hipStream_t stream) {
  (void)in_sizes; (void)n_in; (void)d_ws; (void)ws_size; (void)out_size;
  const float* query = (const float*)d_in[0];
  const float* value = (const float*)d_in[1];
  // d_in[2] = mask: all-true; its effect (look-back pad masking) is explicit.
  const float* Wq = (const float*)d_in[3];
  const float* bq = (const float*)d_in[4];
  const float* Wv = (const float*)d_in[5];
  const float* bv = (const float*)d_in[6];
  const float* Wo = (const float*)d_in[7];
  const float* bo = (const float*)d_in[8];
  const float* rm = (const float*)d_in[9];
  float* out = (float*)d_out;

  stage1_kernel<<<1088, 256, 0, stream>>>(query, Wq, bq, value, Wv, bv, rm);
  hash_kernel<<<1024, 256, 0, stream>>>();
  sort_kernel<<<64, 128, 0, stream>>>();
  counts_kernel<<<dim3(16, 128), 256, 0, stream>>>();
  passA_kernel<<<4096, 256, 0, stream>>>();
  combine_kernel<<<8192, 256, 0, stream>>>();
  mgemm2<<<dim3(64, 4), 256, 0, stream>>>(Wo, bo, out);
}

// Round 17
// 246.325 us; speedup vs baseline: 1.0927x; 1.0611x over previous
//
#include <hip/hip_runtime.h>

// Problem constants: B=2, L=4096, D_MODEL=512, HEAD=8, D_K=64,
// N_BUCKETS=128, ROUNDS=4, 64 chunks of 64 sorted positions, window=128.
#define L4   4096
#define DK   64
#define NR   4
#define NB   128
#define WIN  128
#define DM   512
#define BH   16
#define BIGF 1000000000.0f

typedef short v8s __attribute__((ext_vector_type(8)));
typedef float v4f __attribute__((ext_vector_type(4)));

__device__ __forceinline__ unsigned short f2bf(float x) {
  union { float f; unsigned u; } v; v.f = x;
  const unsigned r = (v.u + 0x7FFFu + ((v.u >> 16) & 1u)) >> 16;
  return (unsigned short)r;
}
__device__ __forceinline__ float bf2f(unsigned short u) {
  union { unsigned u; float f; } v; v.u = ((unsigned)u) << 16;
  return v.f;
}
__device__ __forceinline__ ushort4 f2bf4(const float4 x) {
  ushort4 r; r.x = f2bf(x.x); r.y = f2bf(x.y); r.z = f2bf(x.z); r.w = f2bf(x.w);
  return r;
}

// ---- static device workspace (deterministic, fully rewritten per call) ----
__device__ float g_fqn[(size_t)BH * L4 * DK];            // normalized q f32 (hash path)
__device__ unsigned short g_fqb[(size_t)BH * L4 * DK];   // normalized q bf16 (scores)
__device__ unsigned short g_fvb[(size_t)BH * L4 * DK];   // v bf16 (PV)
__device__ float g_rmnT[NR * 64 * DK];                   // normalized rand matrix [r][k][d]
__device__ int   g_hash [BH * NR * L4];
__device__ int   g_sidx [BH * NR * L4];                  // sorted pos -> original l
__device__ int   g_shash[BH * NR * L4];
__device__ int   g_inv  [BH * NR * L4];                  // original l -> sorted pos
__device__ unsigned char g_cnt[(size_t)BH * L4 * WIN];   // packed dup-key counts: n0|n1<<3|n2<<6
__device__ float2 g_stat[BH * NR * L4];                  // per-round row (max, sumexp) by spos
__device__ unsigned short g_osortb[(size_t)BH * NR * L4 * DK]; // UNNORMALIZED per-round out bf16, sorted
__device__ unsigned short g_xb[(size_t)2 * L4 * DM];     // concat-head attention out (bf16)

// ===== stage 1a: qproj (blocks [0,512)) + rmnorm ([512,576)); bodies unchanged =====
__global__ __launch_bounds__(256) void stage1_kernel(const float* __restrict__ A,
                                                     const float* __restrict__ Wq,
                                                     const float* __restrict__ bq,
                                                     const float* __restrict__ rm)
{
  __shared__ __align__(16) char smem[27648];
  const int bid = blockIdx.x;
  const int tid = threadIdx.x;
  if (bid < 512) {
    // ---------------- qproj body (R9/R10 passing version) ----------------
    float (*As)[132] = (float(*)[132])smem;                 // 16896 B
    float (*Bs)[68]  = (float(*)[68])(smem + 16896);        //  8704 B
    const int m0 = (bid & 63) * 128;
    const int n0 = (bid >> 6) * 64;
    const int am = tid & 127, ak0 = (tid >> 7) * 16;
    const int bn = tid & 63,  bk0 = (tid >> 6) * 8;
    const float* arow = A + (size_t)(m0 + am) * DM + ak0;
    const float* brow = Wq + (size_t)(n0 + bn) * DM + bk0;
    float4 pa0 = *(const float4*)(arow);
    float4 pa1 = *(const float4*)(arow + 4);
    float4 pa2 = *(const float4*)(arow + 8);
    float4 pa3 = *(const float4*)(arow + 12);
    float4 pb0 = *(const float4*)(brow);
    float4 pb1 = *(const float4*)(brow + 4);
    const int lane = tid & 63, w = tid >> 6;
    const int ng = lane & 15, mgl = lane >> 4;
    const int mbase = (w * 4 + mgl) * 8;
    const int nbase = ng * 4;
    float acc[8][4] = {};
    for (int kt = 0; kt < DM; kt += 32) {
      __syncthreads();
      As[ak0 +  0][am] = pa0.x; As[ak0 +  1][am] = pa0.y; As[ak0 +  2][am] = pa0.z; As[ak0 +  3][am] = pa0.w;
      As[ak0 +  4][am] = pa1.x; As[ak0 +  5][am] = pa1.y; As[ak0 +  6][am] = pa1.z; As[ak0 +  7][am] = pa1.w;
      As[ak0 +  8][am] = pa2.x; As[ak0 +  9][am] = pa2.y; As[ak0 + 10][am] = pa2.z; As[ak0 + 11][am] = pa2.w;
      As[ak0 + 12][am] = pa3.x; As[ak0 + 13][am] = pa3.y; As[ak0 + 14][am] = pa3.z; As[ak0 + 15][am] = pa3.w;
      Bs[bk0 + 0][bn] = pb0.x; Bs[bk0 + 1][bn] = pb0.y; Bs[bk0 + 2][bn] = pb0.z; Bs[bk0 + 3][bn] = pb0.w;
      Bs[bk0 + 4][bn] = pb1.x; Bs[bk0 + 5][bn] = pb1.y; Bs[bk0 + 6][bn] = pb1.z; Bs[bk0 + 7][bn] = pb1.w;
      __syncthreads();
      if (kt + 32 < DM) {
        pa0 = *(const float4*)(arow + kt + 32);
        pa1 = *(const float4*)(arow + kt + 36);
        pa2 = *(const float4*)(arow + kt + 40);
        pa3 = *(const float4*)(arow + kt + 44);
        pb0 = *(const float4*)(brow + kt + 32);
        pb1 = *(const float4*)(brow + kt + 36);
      }
      #pragma unroll
      for (int kk = 0; kk < 32; ++kk) {
        const float4 a0 = *(const float4*)&As[kk][mbase];
        const float4 a1 = *(const float4*)&As[kk][mbase + 4];
        const float4 bv4 = *(const float4*)&Bs[kk][nbase];
        const float amv[8] = {a0.x, a0.y, a0.z, a0.w, a1.x, a1.y, a1.z, a1.w};
        const float bnv[4] = {bv4.x, bv4.y, bv4.z, bv4.w};
        #pragma unroll
        for (int i = 0; i < 8; ++i)
          #pragma unroll
          for (int j = 0; j < 4; ++j)
            acc[i][j] = fmaf(amv[i], bnv[j], acc[i][j]);
      }
    }
    #pragma unroll
    for (int j = 0; j < 4; ++j) {
      const float bb = bq[n0 + nbase + j];
      #pragma unroll
      for (int i = 0; i < 8; ++i) acc[i][j] += bb;
    }
    float sc[8];
    #pragma unroll
    for (int i = 0; i < 8; ++i) {
      float s = acc[i][0] * acc[i][0];
      s = fmaf(acc[i][1], acc[i][1], s);
      s = fmaf(acc[i][2], acc[i][2], s);
      s = fmaf(acc[i][3], acc[i][3], s);
      s += __shfl_xor(s, 1);
      s += __shfl_xor(s, 2);
      s += __shfl_xor(s, 4);
      s += __shfl_xor(s, 8);
      sc[i] = 1.0f / sqrtf(s);
    }
    const int bh = (m0 >> 12) * 8 + (n0 >> 6);
    const int lb = (m0 & (L4 - 1)) + mbase;
    #pragma unroll
    for (int i = 0; i < 8; ++i) {
      const size_t idx = ((size_t)bh * L4 + lb + i) * DK + nbase;
      float4 o;
      o.x = acc[i][0] * sc[i]; o.y = acc[i][1] * sc[i];
      o.z = acc[i][2] * sc[i]; o.w = acc[i][3] * sc[i];
      *(float4*)(g_fqn + idx) = o;
      *(ushort4*)(g_fqb + idx) = f2bf4(o);
    }
  } else {
    // --- rmnorm body (4 rows/block) ---
    const int dr = (bid - 512) * 4 + (tid >> 6);   // d*4 + r
    const int k = tid & 63;
    const float v = rm[dr * 64 + k];
    float s = v * v;
    #pragma unroll
    for (int off = 32; off; off >>= 1) s += __shfl_xor(s, off);
    const int d = dr >> 2, r = dr & 3;
    g_rmnT[(r * 64 + k) * DK + d] = v / sqrtf(s);
  }
}

// ===== stage 2 (fused, pipe-complementary): vproj [0,512) | hash [512,1536).
// vproj is LDS/VMEM/MFMA-bound; hash uses ZERO LDS (VALU + scalar-mem) -> the two
// block types occupy disjoint pipes and co-schedule (m114). vproj is placed first
// in dispatch order so its LDS-limited blocks land before the 0-LDS hash blocks
// backfill the same CUs -> co-residency from t=0 (unlike the R10 same-pipe case).
__global__ __launch_bounds__(256) void stage2_kernel(const float* __restrict__ Vf,
                                                     const float* __restrict__ Wv,
                                                     const float* __restrict__ bv)
{
  __shared__ __align__(16) char smem[27648];
  const int bid = blockIdx.x;
  const int tid = threadIdx.x;
  if (bid < 512) {
    // ------------- V projection, bf16 MFMA (unchanged body) -------------
    unsigned short (*As)[72] = (unsigned short(*)[72])smem;          // 18432 B
    unsigned short (*Bs)[72] = (unsigned short(*)[72])(smem + 18432); //  9216 B
    const int m0 = (bid & 63) * 128;
    const int n0 = (bid >> 6) * 64;
    const int lane = tid & 63, w = tid >> 6;
    const int li = lane & 15, lq = lane >> 4;
    v4f acc[2][4];
    #pragma unroll
    for (int mt = 0; mt < 2; ++mt)
      #pragma unroll
      for (int jt = 0; jt < 4; ++jt) acc[mt][jt] = (v4f){0.f, 0.f, 0.f, 0.f};
    for (int kt = 0; kt < DM; kt += 64) {
      __syncthreads();
      {
        const int row = tid >> 1, h = tid & 1;
        const float* src = Vf + (size_t)(m0 + row) * DM + kt + h * 32;
        #pragma unroll
        for (int u = 0; u < 4; ++u) {
          const float4 x = *(const float4*)(src + u * 8);
          const float4 y = *(const float4*)(src + u * 8 + 4);
          *(ushort4*)&As[row][h * 32 + u * 8]     = f2bf4(x);
          *(ushort4*)&As[row][h * 32 + u * 8 + 4] = f2bf4(y);
        }
      }
      {
        const int row = tid >> 2, p = tid & 3;
        const float* src = Wv + (size_t)(n0 + row) * DM + kt + p * 16;
        #pragma unroll
        for (int u = 0; u < 2; ++u) {
          const float4 x = *(const float4*)(src + u * 8);
          const float4 y = *(const float4*)(src + u * 8 + 4);
          *(ushort4*)&Bs[row][p * 16 + u * 8]     = f2bf4(x);
          *(ushort4*)&Bs[row][p * 16 + u * 8 + 4] = f2bf4(y);
        }
      }
      __syncthreads();
      #pragma unroll
      for (int ks = 0; ks < 2; ++ks) {
        const v8s aq0 = *(const v8s*)&As[w * 32 + li][ks * 32 + lq * 8];
        const v8s aq1 = *(const v8s*)&As[w * 32 + 16 + li][ks * 32 + lq * 8];
        #pragma unroll
        for (int jt = 0; jt < 4; ++jt) {
          const v8s bk = *(const v8s*)&Bs[jt * 16 + li][ks * 32 + lq * 8];
          acc[0][jt] = __builtin_amdgcn_mfma_f32_16x16x32_bf16(aq0, bk, acc[0][jt], 0, 0, 0);
          acc[1][jt] = __builtin_amdgcn_mfma_f32_16x16x32_bf16(aq1, bk, acc[1][jt], 0, 0, 0);
        }
      }
    }
    #pragma unroll
    for (int mt = 0; mt < 2; ++mt)
      #pragma unroll
      for (int jt = 0; jt < 4; ++jt)
        #pragma unroll
        for (int reg = 0; reg < 4; ++reg) {
          const int m = m0 + w * 32 + mt * 16 + lq * 4 + reg;
          const int n = n0 + jt * 16 + li;
          const float vv = acc[mt][jt][reg] + bv[n];
          const int bh = (m >> 12) * 8 + (n >> 6);
          const int l = m & (L4 - 1);
          g_fvb[((size_t)bh * L4 + l) * DK + (n & 63)] = f2bf(vv);
        }
  } else {
    // ---------------- hash body (unchanged; zero LDS) ----------------
    const int w = __builtin_amdgcn_readfirstlane(tid >> 6);   // round (wave-uniform)
    const int lane = tid & 63;
    const int row = (bid - 512) * 64 + lane;   // flattened bh*L4 + l
    float q[64];
    #pragma unroll
    for (int du = 0; du < 16; ++du) {
      const float4 v = *(const float4*)(g_fqn + (size_t)row * DK + du * 4);
      q[du * 4 + 0] = v.x; q[du * 4 + 1] = v.y;
      q[du * 4 + 2] = v.z; q[du * 4 + 3] = v.w;
    }
    const float* rmw = g_rmnT + w * (64 * DK);
    float bestP = -BIGF, bestN = -BIGF;
    int idxP = 0, idxN = 0;
    for (int k = 0; k < 64; k += 2) {
      const float* rp0 = rmw + k * DK;        // wave-uniform -> s_load
      const float* rp1 = rp0 + DK;
      float a0 = 0.f, a1 = 0.f;
      #pragma unroll
      for (int d = 0; d < 64; ++d) {
        a0 = fmaf(q[d], rp0[d], a0);
        a1 = fmaf(q[d], rp1[d], a1);
      }
      if (a0 > bestP)  { bestP = a0;  idxP = k; }
      if (-a0 > bestN) { bestN = -a0; idxN = k; }
      if (a1 > bestP)  { bestP = a1;  idxP = k + 1; }
      if (-a1 > bestN) { bestN = -a1; idxN = k + 1; }
    }
    const int idx = (bestP >= bestN) ? idxP : 64 + idxN;
    const int bh = row >> 12, l = row & (L4 - 1);
    g_hash[(bh * NR + w) * L4 + l] = idx;
  }
}

// ------------- stable counting sort of 4096 hashes per (bh, round) -------------
__global__ __launch_bounds__(128) void sort_kernel() {
  __shared__ int chunkHist[64][NB];   // 32 KB
  __shared__ int tot[NB];
  __shared__ int binBase[NB];
  const int bhr = blockIdx.x;         // bh*4 + r
  const int t = threadIdx.x;
  const int* hrow = g_hash + bhr * L4;
  for (int idx = t; idx < 64 * NB; idx += 128) ((int*)chunkHist)[idx] = 0;
  __syncthreads();
  if (t < 64) {
    for (int e = 0; e < 64; ++e) chunkHist[t][hrow[t * 64 + e]]++;
  }
  __syncthreads();
  if (t < NB) { int s = 0; for (int cc = 0; cc < 64; ++cc) s += chunkHist[cc][t]; tot[t] = s; }
  __syncthreads();
  if (t == 0) { int run = 0; for (int h = 0; h < NB; ++h) { binBase[h] = run; run += tot[h]; } }
  __syncthreads();
  if (t < NB) {
    int run = binBase[t];
    for (int cc = 0; cc < 64; ++cc) { const int tmp = chunkHist[cc][t]; chunkHist[cc][t] = run; run += tmp; }
  }
  __syncthreads();
  if (t < 64) {
    for (int e = 0; e < 64; ++e) {
      const int l = t * 64 + e;
      const int h = hrow[l];
      const int p = chunkHist[t][h]++;
      g_sidx [bhr * L4 + p] = l;
      g_shash[bhr * L4 + p] = h;
      g_inv  [bhr * L4 + l] = p;
    }
  }
}

// ---- duplicate-key counts (bug-faithful), PACKED: n0 | n1<<3 | n2<<6 per byte ----
__global__ __launch_bounds__(256) void counts_kernel() {
  const int bh = blockIdx.x;
  const int l0 = blockIdx.y * 32;
  const int j = threadIdx.x & 127;
  const int lh = threadIdx.x >> 7;   // 0..1
  for (int u = 0; u < 16; ++u) {
    const int l = l0 + u * 2 + lh;
    int a[4];
    #pragma unroll
    for (int r = 0; r < NR; ++r) {
      const int base = (bh * NR + r) * L4;
      const int spos = g_inv[base + l];
      const int c = spos >> 6;
      // shared pad sentinel across rounds (reference's 1e9==1e9 pad equality)
      a[r] = (c == 0 && j < 64) ? (1 << 20) : g_sidx[base + c * 64 - 64 + j];
    }
    const int c01 = a[0] == a[1], c02 = a[0] == a[2], c03 = a[0] == a[3];
    const int c12 = a[1] == a[2], c13 = a[1] == a[3], c23 = a[2] == a[3];
    const int n0 = 1 + 2 * c01 + c02 + c03 + c12 + c23;
    const int n1 = 1 + c02 + c12 + 2 * c13;
    const int n2 = 1 + c03 + c23;
    g_cnt[((size_t)bh * L4 + l) * WIN + j] = (unsigned char)(n0 | (n1 << 3) | (n2 << 6));
  }
}

// ==== fused attention pass: MFMA QK^T + masks -> (m, Z) stat -> P'=exp(s-m) bf16
// in LDS -> V gather -> PV MFMA -> UNNORMALIZED O' bf16 to g_osortb.
// 1D grid with XCD-chunk swizzle (bijective; window-overlap re-reads stay in-XCD).
__global__ __launch_bounds__(256) void passA_kernel() {
  const int flat = (blockIdx.x & 7) * 512 + (blockIdx.x >> 3);
  const int c = flat & 63, r = (flat >> 6) & 3, bh = flat >> 8;
  const int base = (bh * NR + r) * L4;
  const int s0 = c * 64;
  const bool use_cnt = (r != 3);   // round-3 counts are identically 1
  const int cnt_sh = (r == 2) ? 6 : r * 3;    // block-uniform unpack shift
  const int cnt_msk = (r == 2) ? 3 : 7;
  __shared__ __align__(16) char smem[35840];
  unsigned short (*Qb)[72] = (unsigned short(*)[72])smem;            //  9216 B
  unsigned short (*Kb)[72] = (unsigned short(*)[72])(smem + 9216);   // 18432 B
  unsigned char (*cnt8)[128] = (unsigned char(*)[128])(smem + 27648); // 8192 B
  unsigned short (*Pt)[136] = (unsigned short(*)[136])smem;          // 17408 B (phase 2)
  unsigned short (*Vt)[136] = (unsigned short(*)[136])(smem + 17408); // 17408 B (phase 2)
  __shared__ int qi_s[64], qh_s[64], ki_s[128], kh_s[128];
  __shared__ float lutl[9];
  const int tid = threadIdx.x;
  if (tid < 9) lutl[tid] = __logf((float)(tid < 1 ? 1 : tid));
  {
    const int i = tid >> 2, p = tid & 3;
    const int qi = g_sidx[base + s0 + i];
    if (p == 0) { qi_s[i] = qi; qh_s[i] = g_shash[base + s0 + i]; }
    const uint4* src = (const uint4*)(g_fqb + ((size_t)bh * L4 + qi) * DK);
    *(uint4*)&Qb[i][p * 16]     = src[2 * p];
    *(uint4*)&Qb[i][p * 16 + 8] = src[2 * p + 1];
    if (use_cnt) {
      const uint4* cs = (const uint4*)(g_cnt + ((size_t)bh * L4 + qi) * WIN);
      *(uint4*)&cnt8[i][p * 32]      = cs[2 * p];
      *(uint4*)&cnt8[i][p * 32 + 16] = cs[2 * p + 1];
    }
  }
  {
    const int j = tid >> 1, h = tid & 1;
    const bool pad = (c == 0) && (j < 64);
    if (pad) {
      if (h == 0) { ki_s[j] = -1; kh_s[j] = (1 << 30); }
      const uint4 z = make_uint4(0, 0, 0, 0);
      #pragma unroll
      for (int u = 0; u < 4; ++u) *(uint4*)&Kb[j][h * 32 + u * 8] = z;
    } else {
      const int ki = g_sidx[base + s0 - 64 + j];
      if (h == 0) { ki_s[j] = ki; kh_s[j] = g_shash[base + s0 - 64 + j]; }
      const uint4* src = (const uint4*)(g_fqb + ((size_t)bh * L4 + ki) * DK);
      #pragma unroll
      for (int u = 0; u < 4; ++u) *(uint4*)&Kb[j][h * 32 + u * 8] = src[h * 4 + u];
    }
  }
  __syncthreads();
  const int lane = tid & 63, w = tid >> 6;
  const int i0 = w * 16;
  const int li = lane & 15, lq = lane >> 4;
  v4f acc[8];
  #pragma unroll
  for (int jt = 0; jt < 8; ++jt) acc[jt] = (v4f){0.f, 0.f, 0.f, 0.f};
  #pragma unroll
  for (int ks = 0; ks < 2; ++ks) {
    const v8s aq = *(const v8s*)&Qb[i0 + li][ks * 32 + lq * 8];
    #pragma unroll
    for (int jt = 0; jt < 8; ++jt) {
      const v8s bk = *(const v8s*)&Kb[jt * 16 + li][ks * 32 + lq * 8];
      acc[jt] = __builtin_amdgcn_mfma_f32_16x16x32_bf16(aq, bk, acc[jt], 0, 0, 0);
    }
  }
  // masks (exact ordering), then per-row max / sumexp
  float mrow[4];
  #pragma unroll
  for (int reg = 0; reg < 4; ++reg) {
    const int i = i0 + lq * 4 + reg;
    const int qi = qi_s[i], qh = qh_s[i];
    float lm = -3.0f * BIGF;
    #pragma unroll
    for (int jt = 0; jt < 8; ++jt) {
      const int j = jt * 16 + li;
      const int ki = ki_s[j], kh = kh_s[j];
      float s;
      if (ki < 0) {
        s = 0.f - BIGF - BIGF - BIGF;
      } else {
        s = acc[jt][reg] * 0.125f;
        if (qh != kh) s -= BIGF;
        if (qi < ki)  s -= BIGF;
        if (qi == ki) s -= 100000.0f;
        if (use_cnt) s -= lutl[(cnt8[i][j] >> cnt_sh) & cnt_msk];
      }
      acc[jt][reg] = s;
      lm = fmaxf(lm, s);
    }
    #pragma unroll
    for (int off = 1; off < 16; off <<= 1) lm = fmaxf(lm, __shfl_xor(lm, off));
    mrow[reg] = lm;
    float ps = 0.f;
    #pragma unroll
    for (int jt = 0; jt < 8; ++jt) ps += __expf(acc[jt][reg] - lm);
    #pragma unroll
    for (int off = 1; off < 16; off <<= 1) ps += __shfl_xor(ps, off);
    if (li == 0) g_stat[base + s0 + i] = make_float2(lm, ps);
  }
  __syncthreads();   // all waves done reading Qb/Kb/cnt8; reuse as Pt|Vt
  #pragma unroll
  for (int reg = 0; reg < 4; ++reg) {
    const int i = i0 + lq * 4 + reg;
    #pragma unroll
    for (int jt = 0; jt < 8; ++jt)
      Pt[i][jt * 16 + li] = f2bf(__expf(acc[jt][reg] - mrow[reg]));
  }
  // V gather, transposed into LDS: Vt[d][j]
  {
    const int j = tid >> 1, h = tid & 1;
    const bool pad = (c == 0) && (j < 64);
    if (pad) {
      #pragma unroll
      for (int d = 0; d < 32; ++d) Vt[h * 32 + d][j] = 0;
    } else {
      const int ki = g_sidx[base + s0 - 64 + j];
      const uint4* src = (const uint4*)(g_fvb + ((size_t)bh * L4 + ki) * DK);
      #pragma unroll
      for (int u = 0; u < 4; ++u) {
        const uint4 v = src[h * 4 + u];
        const unsigned short* e = (const unsigned short*)&v;
        #pragma unroll
        for (int t = 0; t < 8; ++t) Vt[h * 32 + u * 8 + t][j] = e[t];
      }
    }
  }
  __syncthreads();
  // PV MFMA; write UNNORMALIZED O' (scale deferred to combine)
  v4f acc2[4];
  #pragma unroll
  for (int dt = 0; dt < 4; ++dt) acc2[dt] = (v4f){0.f, 0.f, 0.f, 0.f};
  #pragma unroll
  for (int ks = 0; ks < 4; ++ks) {
    const v8s pa = *(const v8s*)&Pt[i0 + li][ks * 32 + lq * 8];
    #pragma unroll
    for (int dt = 0; dt < 4; ++dt) {
      const v8s vb = *(const v8s*)&Vt[dt * 16 + li][ks * 32 + lq * 8];
      acc2[dt] = __builtin_amdgcn_mfma_f32_16x16x32_bf16(pa, vb, acc2[dt], 0, 0, 0);
    }
  }
  #pragma unroll
  for (int reg = 0; reg < 4; ++reg) {
    const int i = i0 + lq * 4 + reg;
    unsigned short* orow = g_osortb + ((size_t)(base + s0 + i)) * DK;
    #pragma unroll
    for (int dt = 0; dt < 4; ++dt)
      orow[dt * 16 + li] = f2bf(acc2[dt][reg]);
  }
}

// ------- gather per-round UNNORMALIZED outputs; inline softmax merge; sum rounds -------
__global__ __launch_bounds__(256) void combine_kernel() {
  const int b = blockIdx.x >> 12, l = blockIdx.x & (L4 - 1);
  const int tid = threadIdx.x;
  const int d = tid & 63, h0 = tid >> 6;
  #pragma unroll
  for (int hh = h0; hh < 8; hh += 4) {
    const int bh = b * 8 + hh;
    int sidx[4];
    float m[4], z[4];
    #pragma unroll
    for (int r = 0; r < NR; ++r) {
      const int base = (bh * NR + r) * L4;
      const int s = g_inv[base + l];
      sidx[r] = s;
      const float2 st = g_stat[base + s];
      m[r] = st.x; z[r] = st.y;
    }
    const float M = fmaxf(fmaxf(m[0], m[1]), fmaxf(m[2], m[3]));
    const float Z = z[0] * __expf(m[0] - M) + z[1] * __expf(m[1] - M)
                  + z[2] * __expf(m[2] - M) + z[3] * __expf(m[3] - M);
    const float invZ = 1.0f / Z;
    float v = 0.f;
    #pragma unroll
    for (int r = 0; r < NR; ++r) {
      const int base = (bh * NR + r) * L4;
      const float scale = __expf(m[r] - M) * invZ;
      v += bf2f(g_osortb[((size_t)base + sidx[r]) * DK + d]) * scale;
    }
    g_xb[((size_t)b * L4 + l) * DM + hh * 64 + d] = f2bf(v);
  }
}

// -------- bf16 MFMA GEMM: out = g_xb @ Wo^T + bo ; N-tile 128 --------
__global__ __launch_bounds__(256) void mgemm2(const float* __restrict__ W,
                                              const float* __restrict__ bias,
                                              float* __restrict__ outp)
{
  const int m0 = blockIdx.x * 128;
  const int n0 = blockIdx.y * 128;
  __shared__ unsigned short As[128][72];
  __shared__ unsigned short Bs[128][72];
  const int tid = threadIdx.x;
  const int lane = tid & 63, w = tid >> 6;
  const int li = lane & 15, lq = lane >> 4;
  v4f acc[2][8];
  #pragma unroll
  for (int mt = 0; mt < 2; ++mt)
    #pragma unroll
    for (int jt = 0; jt < 8; ++jt) acc[mt][jt] = (v4f){0.f, 0.f, 0.f, 0.f};
  for (int kt = 0; kt < DM; kt += 64) {
    __syncthreads();
    {
      const int row = tid >> 1, h = tid & 1;
      const unsigned short* src = g_xb + (size_t)(m0 + row) * DM + kt + h * 32;
      #pragma unroll
      for (int u = 0; u < 4; ++u)
        *(uint4*)&As[row][h * 32 + u * 8] = ((const uint4*)src)[u];
    }
    {
      const int row = tid >> 1, h = tid & 1;
      const float* src = W + (size_t)(n0 + row) * DM + kt + h * 32;
      #pragma unroll
      for (int u = 0; u < 4; ++u) {
        const float4 x = *(const float4*)(src + u * 8);
        const float4 y = *(const float4*)(src + u * 8 + 4);
        *(ushort4*)&Bs[row][h * 32 + u * 8]     = f2bf4(x);
        *(ushort4*)&Bs[row][h * 32 + u * 8 + 4] = f2bf4(y);
      }
    }
    __syncthreads();
    #pragma unroll
    for (int ks = 0; ks < 2; ++ks) {
      const v8s aq0 = *(const v8s*)&As[w * 32 + li][ks * 32 + lq * 8];
      const v8s aq1 = *(const v8s*)&As[w * 32 + 16 + li][ks * 32 + lq * 8];
      #pragma unroll
      for (int jt = 0; jt < 8; ++jt) {
        const v8s bk = *(const v8s*)&Bs[jt * 16 + li][ks * 32 + lq * 8];
        acc[0][jt] = __builtin_amdgcn_mfma_f32_16x16x32_bf16(aq0, bk, acc[0][jt], 0, 0, 0);
        acc[1][jt] = __builtin_amdgcn_mfma_f32_16x16x32_bf16(aq1, bk, acc[1][jt], 0, 0, 0);
      }
    }
  }
  #pragma unroll
  for (int mt = 0; mt < 2; ++mt)
    #pragma unroll
    for (int jt = 0; jt < 8; ++jt)
      #pragma unroll
      for (int reg = 0; reg < 4; ++reg) {
        const int m = m0 + w * 32 + mt * 16 + lq * 4 + reg;
        const int n = n0 + jt * 16 + li;
        outp[(size_t)m * DM + n] = acc[mt][jt][reg] + bias[n];
      }
}

extern "C" void kernel_launch(void* const* d_in, const int* in_sizes, int n_in,
                              void* d_out, int out_size, void* d_ws, size_t ws_size,
                              hipStream_t stream) {
  (void)in_sizes; (void)n_in; (void)d_ws; (void)ws_size; (void)out_size;
  const float* query = (const float*)d_in[0];
  const float* value = (const float*)d_in[1];
  // d_in[2] = mask: all-true; its effect (look-back pad masking) is explicit.
  const float* Wq = (const float*)d_in[3];
  const float* bq = (const float*)d_in[4];
  const float* Wv = (const float*)d_in[5];
  const float* bv = (const float*)d_in[6];
  const float* Wo = (const float*)d_in[7];
  const float* bo = (const float*)d_in[8];
  const float* rm = (const float*)d_in[9];
  float* out = (float*)d_out;

  stage1_kernel<<<576, 256, 0, stream>>>(query, Wq, bq, rm);
  stage2_kernel<<<1536, 256, 0, stream>>>(value, Wv, bv);
  sort_kernel<<<64, 128, 0, stream>>>();
  counts_kernel<<<dim3(16, 128), 256, 0, stream>>>();
  passA_kernel<<<4096, 256, 0, stream>>>();
  combine_kernel<<<8192, 256, 0, stream>>>();
  mgemm2<<<dim3(64, 4), 256, 0, stream>>>(Wo, bo, out);
}